// Round 10
// baseline (497.296 us; speedup 1.0000x reference)
//
#include <hip/hip_runtime.h>
#include <hip/hip_bf16.h>
#include <stdint.h>

// ---------------------------------------------------------------------------
// LoRA attention, fully bf16-MFMA path.
//   y = x@(W + B@A)^T for q,k,v ; flash-attn causal (swapped-operand) ;
//   o-proj to fp32.
// Shapes: B=4 S=2048 D=2048 H=16 HD=128 R=16. M = B*S = 8192.
// ---------------------------------------------------------------------------

#define L2E 1.4426950408889634f
#define SMSCALE 0.08838834764831845f
#define NEGBIG -3.0e38f

typedef __attribute__((ext_vector_type(4))) float f32x4;
typedef __attribute__((ext_vector_type(16))) float f32x16;
typedef __attribute__((ext_vector_type(8))) __bf16 bfrag;   // 8 bf16 = 4 VGPR

#if __has_builtin(__builtin_amdgcn_exp2f)
#define EXP2 __builtin_amdgcn_exp2f
#else
#define EXP2 exp2f
#endif

// Explicit LDS-DMA drain: a late-landing global_load_lds must never cross a
// barrier into a region that gets read/reused (r2 replay-race lesson).
#define DRAIN_VM                                      \
  do {                                                \
    asm volatile("s_waitcnt vmcnt(0)" ::: "memory");  \
    __builtin_amdgcn_sched_barrier(0);                \
  } while (0)

static __device__ __forceinline__ unsigned short f2bf(float f) {
  union { float f; unsigned u; } v; v.f = f;
  unsigned r = v.u + 0x7FFFu + ((v.u >> 16) & 1u);   // RNE
  return (unsigned short)(r >> 16);
}

static __device__ __forceinline__ void gload16(const void* g, void* l) {
  __builtin_amdgcn_global_load_lds(
      (const __attribute__((address_space(1))) void*)g,
      (__attribute__((address_space(3))) void*)l, 16, 0, 0);
}

// ---------------------------------------------------------------------------
// Fused prep: blocks 0..8191 convert x -> bf16; blocks 8192..16383 fold
// Wall[y][n][k] = W_y[n][k] + sum_r B_y[n][r]*A_y[r][k] -> bf16 (y: q,k,v,o).
// ---------------------------------------------------------------------------
struct F4 {
  const float* W[4];
  const float* A[4];
  const float* Bm[4];
};

__global__ __launch_bounds__(256) void k_prep(F4 f, const float* __restrict__ x,
                                              unsigned short* __restrict__ xbf,
                                              unsigned short* __restrict__ Wall) {
  const int bid = blockIdx.x;
  if (bid < 8192) {
    const size_t i = ((size_t)bid * 256 + threadIdx.x) * 8;
    unsigned short o[8];
#pragma unroll
    for (int j = 0; j < 8; ++j) o[j] = f2bf(x[i + j]);
    *(uint4*)(xbf + i) = *(const uint4*)o;
    return;
  }
  const int y = (bid - 8192) >> 11;
  const int n = (bid - 8192) & 2047;
  const int k0 = threadIdx.x * 8;
  const float* W = f.W[y];
  const float* Aa = f.A[y];
  const float* Bm = f.Bm[y];
  const float* wr = W + (size_t)n * 2048 + k0;
  float acc[8];
#pragma unroll
  for (int j = 0; j < 8; ++j) acc[j] = wr[j];
#pragma unroll 4
  for (int r = 0; r < 16; ++r) {
    float b = Bm[n * 16 + r];
    const float* ar = Aa + (size_t)r * 2048 + k0;
#pragma unroll
    for (int j = 0; j < 8; ++j) acc[j] = fmaf(b, ar[j], acc[j]);
  }
  unsigned short o[8];
#pragma unroll
  for (int j = 0; j < 8; ++j) o[j] = f2bf(acc[j]);
  *(uint4*)(Wall + (((size_t)y * 2048 + n) * 2048) + k0) = *(const uint4*)o;
}

// ---------------------------------------------------------------------------
// GEMM5 (B-direct variant of the r7 structure):
//   C[m][n] = sum_k A[m][k] * Bw[n][k],  M=8192 N=2048 K=2048
// 256x256 tile, BK=64, 8 waves (2Mx4N), 16x16x32 MFMA.
// A: double-buffered LDS via global_load_lds (64 KiB total), r7-identical
//    layout ([2 buf][2 K-half][256 rows][32 k], chunk c at pos c^((row>>1)&3)).
// B: DIRECT global->VGPR (no LDS). Per tile 8 b128 loads/wave; each instr
//    touches 16 cache lines, 4 lanes/line; B panel 1 MB/block, L2/L3-hot.
//    Removes 96 KB/tile of LDS traffic (37%) and halves DMA count.
// Per-tile schedule (ONE barrier):
//   ds_read A.k0(8) | MFMA k0x16 (auto vmcnt(0) retires B(T) issued last tile)
//   ds_read A.k1(8) | MFMA k1x16
//   STAGE_A(T+1) [A x4 dma] ; issue B(T+1) [B x8] ; vmcnt(8) retires A-dma
//   s_barrier
// Ledger: FIFO [A4,B8]; vmcnt(8) leaves B in flight across the barrier (its
// latency hides under next tile's 16 ds_reads); A-dbuf overwrite margin = 2
// barriers; B-regs single-buffered, WAR enforced by register dependence.
// MODE 0: bf16 -> [B,H,S,HD] scaled. MODE 1: fp32 flat. MODE 2: bf16 [B,H,HD,S].
// ---------------------------------------------------------------------------
template <int MODE>
__global__ __launch_bounds__(512, 2) void k_gemm5(const unsigned short* __restrict__ A,
                                                  const unsigned short* __restrict__ Bw,
                                                  void* __restrict__ Cout, float scale) {
  __shared__ __align__(16) unsigned char lds[65536];   // A only: 2 buf x 32 KB
  const int tid = threadIdx.x, ln = tid & 63;
  const int w = tid >> 6, g = ln >> 4, cc = ln & 15;
  const int wm = w >> 2, wn = w & 3;
  const int bid = blockIdx.x;
  const int wg = (bid & 7) * 32 + (bid >> 3);   // bijective XCD swizzle (256 wgs)
  const int m0 = (wg >> 3) * 256, n0 = (wg & 7) * 256;

  // A staging constants (r7-identical)
  int soff[2], sdst[2];
#pragma unroll
  for (int i = 0; i < 2; ++i) {
    int cid = i * 512 + tid, r = cid >> 2, p = cid & 3;
    int sc = p ^ ((r >> 1) & 3);
    soff[i] = r * 2048 + sc * 8;      // + m0*2048 + kt + h*32
    sdst[i] = cid * 16;               // + buf*32768 + h*16384
  }
  // A ds_read offsets
  int aro[8];
#pragma unroll
  for (int fm = 0; fm < 8; ++fm) {
    int r = wm * 128 + fm * 16 + cc;
    aro[fm] = r * 64 + ((g ^ ((r >> 1) & 3)) << 4);
  }
  // B direct-load base: row = n0 + wn*64 + fn*16 + cc, k-sub = g*8
  const unsigned short* Bg = Bw + (size_t)(n0 + wn * 64 + cc) * 2048 + g * 8;

#define STAGE_A(b, kt, h)                                                   \
  do {                                                                      \
    _Pragma("unroll")                                                       \
    for (int i = 0; i < 2; ++i)                                             \
      gload16(A + (size_t)m0 * 2048 + soff[i] + (kt) + (h) * 32,            \
              lds + (b) * 32768 + (h) * 16384 + sdst[i]);                   \
  } while (0)
#define ISSUE_B(kt)                                                         \
  do {                                                                      \
    _Pragma("unroll")                                                       \
    for (int ks = 0; ks < 2; ++ks)                                          \
      _Pragma("unroll")                                                     \
      for (int fn = 0; fn < 4; ++fn)                                        \
        bfr[ks][fn] = *(const bfrag*)(Bg + (size_t)fn * 32768 + (kt) +      \
                                      ks * 32);                             \
  } while (0)

  f32x4 acc[8][4] = {};
  bfrag bfr[2][4];

  // prologue: stage A(0) [A x4], issue B(0) [B x8], retire A, barrier
  STAGE_A(0, 0, 0); STAGE_A(0, 0, 1);
  __builtin_amdgcn_sched_barrier(0);
  ISSUE_B(0);
  __builtin_amdgcn_sched_barrier(0);
  asm volatile("s_waitcnt vmcnt(8)" ::: "memory");
  __builtin_amdgcn_s_barrier();
  __builtin_amdgcn_sched_barrier(0);

  for (int T = 0; T < 32; ++T) {
    const unsigned char* Ab = lds + (T & 1) * 32768;
    bfrag af[8];
    // ---- k-half 0
#pragma unroll
    for (int fm = 0; fm < 8; ++fm)
      af[fm] = *(const bfrag*)(Ab + aro[fm]);
    __builtin_amdgcn_sched_barrier(0);
    __builtin_amdgcn_s_setprio(1);
#pragma unroll
    for (int fm = 0; fm < 8; ++fm)
#pragma unroll
      for (int fn = 0; fn < 4; ++fn)
        acc[fm][fn] = __builtin_amdgcn_mfma_f32_16x16x32_bf16(af[fm], bfr[0][fn],
                                                              acc[fm][fn], 0, 0, 0);
    __builtin_amdgcn_s_setprio(0);
    // ---- k-half 1
#pragma unroll
    for (int fm = 0; fm < 8; ++fm)
      af[fm] = *(const bfrag*)(Ab + 16384 + aro[fm]);
    __builtin_amdgcn_sched_barrier(0);
    __builtin_amdgcn_s_setprio(1);
#pragma unroll
    for (int fm = 0; fm < 8; ++fm)
#pragma unroll
      for (int fn = 0; fn < 4; ++fn)
        acc[fm][fn] = __builtin_amdgcn_mfma_f32_16x16x32_bf16(af[fm], bfr[1][fn],
                                                              acc[fm][fn], 0, 0, 0);
    __builtin_amdgcn_s_setprio(0);
    __builtin_amdgcn_sched_barrier(0);
    // ---- prefetch tile T+1: A-dma first, then B (FIFO [A4,B8] -> vmcnt(8))
    if (T < 31) {
      const int ktn = (T + 1) * 64;
      STAGE_A((T & 1) ^ 1, ktn, 0); STAGE_A((T & 1) ^ 1, ktn, 1);
      __builtin_amdgcn_sched_barrier(0);
      ISSUE_B(ktn);
      __builtin_amdgcn_sched_barrier(0);
      asm volatile("s_waitcnt vmcnt(8)" ::: "memory");
      __builtin_amdgcn_sched_barrier(0);
      __builtin_amdgcn_s_barrier();
      __builtin_amdgcn_sched_barrier(0);
    }
  }
#undef STAGE_A
#undef ISSUE_B

  // ---- epilogue: direct global stores from registers (no LDS use)
#pragma unroll
  for (int fm = 0; fm < 8; ++fm)
#pragma unroll
    for (int fn = 0; fn < 4; ++fn)
#pragma unroll
      for (int r = 0; r < 4; ++r) {
        int row = m0 + wm * 128 + fm * 16 + g * 4 + r;   // m = b*2048+s
        int col = n0 + wn * 64 + fn * 16 + cc;           // n = h*128+hd
        float v = acc[fm][fn][r];
        if (MODE == 0) {
          int b = row >> 11, s = row & 2047, h = col >> 7, hd = col & 127;
          ((unsigned short*)Cout)[(((size_t)b * 16 + h) * 2048 + s) * 128 + hd] =
              f2bf(v * scale);
        } else if (MODE == 2) {
          int b = row >> 11, s = row & 2047, h = col >> 7, hd = col & 127;
          ((unsigned short*)Cout)[(((size_t)b * 16 + h) * 128 + hd) * 2048 + s] =
              f2bf(v);
        } else {
          ((float*)Cout)[(size_t)row * 2048 + col] = v;
        }
      }
}

// ---------------------------------------------------------------------------
// Flash attention, causal, swapped-operand, 32x32x16 MFMA.  (r7-exact)
// Q,K: [B,H,S,HD] bf16 (Q prescaled by SMSCALE*L2E). Vt: [B,H,HD,S] bf16.
// O: [B,S,D] bf16. 8 waves x 32 q-rows, KVBLK=64, dbuf LDS, XOR swizzle.
// Dispatch: heavy-first qb = 7-(bx>>6)  (static; queue regressed in r9).
// ---------------------------------------------------------------------------
__global__ __launch_bounds__(512) void k_attn(const unsigned short* __restrict__ Q,
                                              const unsigned short* __restrict__ K,
                                              const unsigned short* __restrict__ Vt,
                                              unsigned short* __restrict__ O) {
  __shared__ __align__(16) unsigned char lds[65536];   // 2 x (16K K + 16K V)
  const int tid = threadIdx.x;
  const int ln = tid & 63, w = tid >> 6;
  const int l31 = ln & 31, hi = ln >> 5;
  const int rk = l31 & 15;
  const int bx = blockIdx.x;
  const int qb = 7 - (bx >> 6);          // heavy-first dispatch order
  const int bh = bx & 63;
  const int q0 = qb * 256;
  const size_t base = (size_t)bh * 2048 * 128;
  const unsigned short* Qb = Q + base;
  const unsigned short* Kb = K + base;
  const unsigned short* Vb = Vt + base;

  const int qw0 = q0 + w * 32;
  const int qg = qw0 + l31;

  // Q fragments (B-operand: col q = lane&31, d = dc*16 + hi*8 + j)
  bfrag qf[8];
#pragma unroll
  for (int dc = 0; dc < 8; ++dc)
    qf[dc] = *(const bfrag*)(Qb + (size_t)qg * 128 + dc * 16 + hi * 8);

  f32x16 o[4] = {};            // O^T acc: [d = db*32 + pat(r,hi)][q = lane&31]
  float m_r = NEGBIG, l_r = 0.f;

  const int nt = q0 / 64 + 4;

  // stage K tile [64][16ch] and V^T tile [64row'][16ch], XOR-16 swizzled
  auto stage = [&](int buf, int k0) {
    unsigned char* Kt = lds + buf * 32768;
    unsigned char* Vl = Kt + 16384;
#pragma unroll
    for (int i = 0; i < 2; ++i) {
      int cid = i * 512 + tid;
      int row = cid >> 4, p = cid & 15, sc = p ^ (row & 15);
      gload16(Kb + (size_t)(k0 + row) * 128 + sc * 8, Kt + cid * 16);
    }
#pragma unroll
    for (int i = 0; i < 2; ++i) {
      int cid = i * 512 + tid;
      int row = cid >> 4, p = cid & 15, sc = p ^ (row & 15);
      int d = (sc >> 3) * 64 + row;
      gload16(Vb + (size_t)d * 2048 + k0 + (sc & 7) * 8, Vl + cid * 16);
    }
  };

  stage(0, 0);
  DRAIN_VM;
  __syncthreads();
  int buf = 0;

  for (int t = 0; t < nt; ++t) {
    const int k0 = t * 64;
    if (t + 1 < nt) stage(buf ^ 1, k0 + 64);   // prefetch under compute

    if (k0 <= qw0 + 31) {                      // wave-uniform causal skip
      const unsigned char* Kt = lds + buf * 32768;
      const unsigned char* Vl = Kt + 16384;

      // ---- S^T = K * Q^T  (k rows, q cols)
      f32x16 s0 = {}, s1 = {};
#pragma unroll
      for (int dc = 0; dc < 8; ++dc) {
        int c = dc * 2 + hi;
        bfrag ka = *(const bfrag*)(Kt + (size_t)l31 * 256 + ((c ^ rk) << 4));
        bfrag kb2 = *(const bfrag*)(Kt + (size_t)(32 + l31) * 256 + ((c ^ rk) << 4));
        s0 = __builtin_amdgcn_mfma_f32_32x32x16_bf16(ka, qf[dc], s0, 0, 0, 0);
        s1 = __builtin_amdgcn_mfma_f32_32x32x16_bf16(kb2, qf[dc], s1, 0, 0, 0);
      }

      // ---- causal mask (diagonal tiles only)
      if (k0 + 63 > qw0) {
#pragma unroll
        for (int r = 0; r < 16; ++r) {
          int ko = (r & 3) + 8 * (r >> 2) + 4 * hi;
          if (k0 + ko > qg) s0[r] = NEGBIG;
          if (k0 + 32 + ko > qg) s1[r] = NEGBIG;
        }
      }

      // ---- row max
      float pmax = s0[0];
#pragma unroll
      for (int r = 1; r < 16; ++r) pmax = fmaxf(pmax, s0[r]);
#pragma unroll
      for (int r = 0; r < 16; ++r) pmax = fmaxf(pmax, s1[r]);
      pmax = fmaxf(pmax, __shfl_xor(pmax, 32));

      // ---- defer-max rescale (T13), log2 domain
      if (!__all(pmax - m_r <= 12.f)) {
        float mn = fmaxf(m_r, pmax);
        float al = EXP2(m_r - mn);
        l_r *= al;
#pragma unroll
        for (int db = 0; db < 4; ++db)
#pragma unroll
          for (int r = 0; r < 16; ++r) o[db][r] *= al;
        m_r = mn;
      }

      // ---- exp2 + pack to bf16 quads
      unsigned qd0[8], qd1[8];
      float rs = 0.f;
#pragma unroll
      for (int s = 0; s < 4; ++s) {
        float p0 = EXP2(s0[4 * s + 0] - m_r), p1 = EXP2(s0[4 * s + 1] - m_r);
        float p2 = EXP2(s0[4 * s + 2] - m_r), p3 = EXP2(s0[4 * s + 3] - m_r);
        rs += (p0 + p1) + (p2 + p3);
        qd0[2 * s] = (unsigned)f2bf(p0) | ((unsigned)f2bf(p1) << 16);
        qd0[2 * s + 1] = (unsigned)f2bf(p2) | ((unsigned)f2bf(p3) << 16);
      }
#pragma unroll
      for (int s = 0; s < 4; ++s) {
        float p0 = EXP2(s1[4 * s + 0] - m_r), p1 = EXP2(s1[4 * s + 1] - m_r);
        float p2 = EXP2(s1[4 * s + 2] - m_r), p3 = EXP2(s1[4 * s + 3] - m_r);
        rs += (p0 + p1) + (p2 + p3);
        qd1[2 * s] = (unsigned)f2bf(p0) | ((unsigned)f2bf(p1) << 16);
        qd1[2 * s + 1] = (unsigned)f2bf(p2) | ((unsigned)f2bf(p3) << 16);
      }
      rs += __shfl_xor(rs, 32);
      l_r += rs;

      // ---- O^T += V^T * P^T
#define PVSTEP(QD, B0, KC)                                                    \
  do {                                                                        \
    unsigned e0 = QD[B0], e1 = QD[B0 + 1], x0 = QD[B0 + 2], x1 = QD[B0 + 3];  \
    unsigned kp0 = hi ? x0 : e0, kp1 = hi ? x1 : e1;                          \
    unsigned sd0 = hi ? e0 : x0, sd1 = hi ? e1 : x1;                          \
    unsigned rc0 = (unsigned)__shfl_xor((int)sd0, 32);                        \
    unsigned rc1 = (unsigned)__shfl_xor((int)sd1, 32);                        \
    unsigned pw[4];                                                           \
    pw[0] = hi ? rc0 : kp0; pw[1] = hi ? rc1 : kp1;                           \
    pw[2] = hi ? kp0 : rc0; pw[3] = hi ? kp1 : rc1;                           \
    bfrag pf = *(bfrag*)pw;                                                   \
    _Pragma("unroll")                                                         \
    for (int db = 0; db < 4; ++db) {                                          \
      int c = (db >> 1) * 8 + KC * 2 + hi;                                    \
      bfrag vf = *(const bfrag*)(Vl + (size_t)((db & 1) * 32 + l31) * 256 +   \
                                 ((c ^ rk) << 4));                            \
      o[db] = __builtin_amdgcn_mfma_f32_32x32x16_bf16(vf, pf, o[db], 0, 0, 0);\
    }                                                                         \
  } while (0)

      PVSTEP(qd0, 0, 0);
      PVSTEP(qd0, 4, 1);
      PVSTEP(qd1, 0, 2);
      PVSTEP(qd1, 4, 3);
#undef PVSTEP
    }
    DRAIN_VM;
    __syncthreads();
    buf ^= 1;
  }

  // ---- epilogue: normalize, transpose O^T -> O via LDS (2 phases, 4 waves)
  float invl = 1.0f / l_r;
  const int b_ = bh >> 4, h_ = bh & 15;
#pragma unroll
  for (int ph = 0; ph < 2; ++ph) {
    if ((w >> 2) == ph) {
      unsigned char* ep = lds + (w & 3) * 8704;   // [32 q][136 d] bf16
#pragma unroll
      for (int db = 0; db < 4; ++db)
#pragma unroll
        for (int s = 0; s < 4; ++s) {
          int d0 = db * 32 + 8 * s + 4 * hi;
          float v0 = o[db][4 * s] * invl, v1 = o[db][4 * s + 1] * invl;
          float v2 = o[db][4 * s + 2] * invl, v3 = o[db][4 * s + 3] * invl;
          uint2 pw;
          pw.x = (unsigned)f2bf(v0) | ((unsigned)f2bf(v1) << 16);
          pw.y = (unsigned)f2bf(v2) | ((unsigned)f2bf(v3) << 16);
          *(uint2*)(ep + l31 * 272 + d0 * 2) = pw;
        }
    }
    __syncthreads();
    if ((w >> 2) == ph) {
      const unsigned char* ep = lds + (w & 3) * 8704;
#pragma unroll
      for (int i = 0; i < 8; ++i) {
        int cid = i * 64 + ln;
        int q = cid >> 4, ch = cid & 15;
        uint4 val = *(const uint4*)(ep + q * 272 + ch * 16);
        *(uint4*)(O + ((size_t)(b_ * 2048 + q0 + w * 32 + q)) * 2048 +
                  h_ * 128 + ch * 8) = val;
      }
    }
    __syncthreads();
  }
}

// ---------------------------------------------------------------------------
extern "C" void kernel_launch(void* const* d_in, const int* in_sizes, int n_in,
                              void* d_out, int out_size, void* d_ws, size_t ws_size,
                              hipStream_t stream) {
  (void)in_sizes; (void)n_in; (void)out_size; (void)ws_size;
  const float* x  = (const float*)d_in[0];
  /* d_in[1] = mask: causal tril, handled analytically */

  char* ws = (char*)d_ws;
  unsigned short* xbf  = (unsigned short*)ws;                        // 32 MiB
  unsigned short* Wall = (unsigned short*)(ws + (size_t)33554432);   // 32 MiB
  unsigned short* Qb   = (unsigned short*)(ws + (size_t)67108864);   // 3 x 32 MiB
  unsigned short* Kb   = Qb + 16777216;
  unsigned short* Vtb  = Kb + 16777216;
  unsigned short* AO   = xbf;   // reuse x_bf16 buffer for attention output

  F4 f;
  f.W[0] = (const float*)d_in[2];  f.A[0] = (const float*)d_in[3];  f.Bm[0] = (const float*)d_in[4];
  f.W[1] = (const float*)d_in[5];  f.A[1] = (const float*)d_in[6];  f.Bm[1] = (const float*)d_in[7];
  f.W[2] = (const float*)d_in[8];  f.A[2] = (const float*)d_in[9];  f.Bm[2] = (const float*)d_in[10];
  f.W[3] = (const float*)d_in[11]; f.A[3] = (const float*)d_in[12]; f.Bm[3] = (const float*)d_in[13];

  k_prep<<<16384, 256, 0, stream>>>(f, x, xbf, Wall);

  k_gemm5<0><<<256, 512, 0, stream>>>(xbf, Wall, Qb, SMSCALE * L2E);           // Q
  k_gemm5<0><<<256, 512, 0, stream>>>(xbf, Wall + 4194304, Kb, 1.0f);          // K
  k_gemm5<2><<<256, 512, 0, stream>>>(xbf, Wall + 8388608, Vtb, 1.0f);         // V^T

  k_attn<<<512, 512, 0, stream>>>(Qb, Kb, Vtb, AO);

  k_gemm5<1><<<256, 512, 0, stream>>>(AO, Wall + 12582912, d_out, 1.0f);       // O
}

// Round 11
// 420.536 us; speedup vs baseline: 1.1825x; 1.1825x over previous
//
#include <hip/hip_runtime.h>
#include <hip/hip_bf16.h>
#include <stdint.h>

// ---------------------------------------------------------------------------
// LoRA attention, fully bf16-MFMA path.
//   y = x@(W + B@A)^T for q,k,v ; flash-attn causal (swapped-operand) ;
//   o-proj to fp32.
// Shapes: B=4 S=2048 D=2048 H=16 HD=128 R=16. M = B*S = 8192.
// ---------------------------------------------------------------------------

#define L2E 1.4426950408889634f
#define SMSCALE 0.08838834764831845f
#define NEGBIG -3.0e38f

typedef __attribute__((ext_vector_type(4))) float f32x4;
typedef __attribute__((ext_vector_type(16))) float f32x16;
typedef __attribute__((ext_vector_type(8))) __bf16 bfrag;   // 8 bf16 = 4 VGPR

#if __has_builtin(__builtin_amdgcn_exp2f)
#define EXP2 __builtin_amdgcn_exp2f
#else
#define EXP2 exp2f
#endif

// Explicit LDS-DMA drain: a late-landing global_load_lds must never cross a
// barrier into a region that gets read/reused (r2 replay-race lesson).
#define DRAIN_VM                                      \
  do {                                                \
    asm volatile("s_waitcnt vmcnt(0)" ::: "memory");  \
    __builtin_amdgcn_sched_barrier(0);                \
  } while (0)

static __device__ __forceinline__ unsigned short f2bf(float f) {
  union { float f; unsigned u; } v; v.f = f;
  unsigned r = v.u + 0x7FFFu + ((v.u >> 16) & 1u);   // RNE
  return (unsigned short)(r >> 16);
}

// packed f32x2 -> bf16x2 (RNE), 1 instr vs ~7 bit-ops (T12)
static __device__ __forceinline__ unsigned cvtpk(float lo, float hi) {
  unsigned r;
  asm("v_cvt_pk_bf16_f32 %0, %1, %2" : "=v"(r) : "v"(lo), "v"(hi));
  return r;
}

static __device__ __forceinline__ void gload16(const void* g, void* l) {
  __builtin_amdgcn_global_load_lds(
      (const __attribute__((address_space(1))) void*)g,
      (__attribute__((address_space(3))) void*)l, 16, 0, 0);
}

// ---------------------------------------------------------------------------
// Fused prep: blocks 0..8191 convert x -> bf16; blocks 8192..16383 fold
// Wall[y][n][k] = W_y[n][k] + sum_r B_y[n][r]*A_y[r][k] -> bf16 (y: q,k,v,o).
// ---------------------------------------------------------------------------
struct F4 {
  const float* W[4];
  const float* A[4];
  const float* Bm[4];
};

__global__ __launch_bounds__(256) void k_prep(F4 f, const float* __restrict__ x,
                                              unsigned short* __restrict__ xbf,
                                              unsigned short* __restrict__ Wall) {
  const int bid = blockIdx.x;
  if (bid < 8192) {
    const size_t i = ((size_t)bid * 256 + threadIdx.x) * 8;
    unsigned short o[8];
#pragma unroll
    for (int j = 0; j < 8; ++j) o[j] = f2bf(x[i + j]);
    *(uint4*)(xbf + i) = *(const uint4*)o;
    return;
  }
  const int y = (bid - 8192) >> 11;
  const int n = (bid - 8192) & 2047;
  const int k0 = threadIdx.x * 8;
  const float* W = f.W[y];
  const float* Aa = f.A[y];
  const float* Bm = f.Bm[y];
  const float* wr = W + (size_t)n * 2048 + k0;
  float acc[8];
#pragma unroll
  for (int j = 0; j < 8; ++j) acc[j] = wr[j];
#pragma unroll 4
  for (int r = 0; r < 16; ++r) {
    float b = Bm[n * 16 + r];
    const float* ar = Aa + (size_t)r * 2048 + k0;
#pragma unroll
    for (int j = 0; j < 8; ++j) acc[j] = fmaf(b, ar[j], acc[j]);
  }
  unsigned short o[8];
#pragma unroll
  for (int j = 0; j < 8; ++j) o[j] = f2bf(acc[j]);
  *(uint4*)(Wall + (((size_t)y * 2048 + n) * 2048) + k0) = *(const uint4*)o;
}

// ---------------------------------------------------------------------------
// GEMM2 (r7-exact, proven 410-us config): 256x256 tile, BK=64, 8 waves,
// 16x16x32 MFMA, 4-phase counted-vmcnt schedule, 128 KiB LDS.
//   C[m][n] = sum_k A[m][k] * Bw[n][k]
// LDS per operand: [2 buf][2 K-half][256 rows][32 k] bf16; chunk c of a row at
// LDS pos c ^ ((row>>1)&3) (bank-balanced, conflict-free b128 reads).
// Ledger: vmcnt(4) retires the k-half consumed 2 phases later; stage ->
// overwrite margin >= 2 barriers; loads never drain mid-loop.
// MODE 1: fp32 flat out (O-proj), grid 256.
// MODE 3: QKV merged, grid 768: seg = bx>>8 (0=Q scaled, 1=K, 2=V^T); Bw and
//   Cout offset by seg; per-block geometry/code identical to MODE 1.
// ---------------------------------------------------------------------------
template <int MODE>
__global__ __launch_bounds__(512, 2) void k_gemm2(const unsigned short* __restrict__ A,
                                                  const unsigned short* __restrict__ Bw,
                                                  void* __restrict__ Cout, float scale) {
  __shared__ __align__(16) unsigned char lds[131072];
  unsigned char* Al = lds;            // A: 2 x 32 KB
  unsigned char* Bl = lds + 65536;    // B: 2 x 32 KB
  const int tid = threadIdx.x, ln = tid & 63;
  const int w = tid >> 6, g = ln >> 4, cc = ln & 15;
  const int wm = w >> 2, wn = w & 3;
  const int bx = blockIdx.x;
  const int seg = (MODE == 3) ? (bx >> 8) : 1;
  const int bid = (MODE == 3) ? (bx & 255) : bx;
  if (MODE == 3) Bw += (size_t)seg * 4194304;
  const int wg = (bid & 7) * 32 + (bid >> 3);   // bijective XCD swizzle (256 wgs)
  const int m0 = (wg >> 3) * 256, n0 = (wg & 7) * 256;

  int soff[2], sdst[2];
#pragma unroll
  for (int i = 0; i < 2; ++i) {
    int cid = i * 512 + tid, r = cid >> 2, p = cid & 3;
    int sc = p ^ ((r >> 1) & 3);
    soff[i] = r * 2048 + sc * 8;      // + base_row*2048 + kt + h*32
    sdst[i] = cid * 16;               // + buf*32768 + h*16384
  }
  int aro[8], bro[4];
#pragma unroll
  for (int fm = 0; fm < 8; ++fm) {
    int r = wm * 128 + fm * 16 + cc;
    aro[fm] = r * 64 + ((g ^ ((r >> 1) & 3)) << 4);
  }
#pragma unroll
  for (int fn = 0; fn < 4; ++fn) {
    int r = wn * 64 + fn * 16 + cc;
    bro[fn] = r * 64 + ((g ^ ((r >> 1) & 3)) << 4);
  }

#define STAGE_A(b, kt, h)                                                   \
  do {                                                                      \
    _Pragma("unroll")                                                       \
    for (int i = 0; i < 2; ++i)                                             \
      gload16(A + (size_t)m0 * 2048 + soff[i] + (kt) + (h) * 32,            \
              Al + (b) * 32768 + (h) * 16384 + sdst[i]);                    \
  } while (0)
#define STAGE_B(b, kt, h)                                                   \
  do {                                                                      \
    _Pragma("unroll")                                                       \
    for (int i = 0; i < 2; ++i)                                             \
      gload16(Bw + (size_t)n0 * 2048 + soff[i] + (kt) + (h) * 32,           \
              Bl + (b) * 32768 + (h) * 16384 + sdst[i]);                    \
  } while (0)

  f32x4 acc[8][4] = {};

  STAGE_A(0, 0, 0); STAGE_B(0, 0, 0);
  STAGE_A(0, 0, 1); STAGE_B(0, 0, 1);
  asm volatile("s_waitcnt vmcnt(4)" ::: "memory");
  __builtin_amdgcn_s_barrier();
  __builtin_amdgcn_sched_barrier(0);

  for (int T = 0; T < 32; ++T) {
    const int buf = T & 1;
    const unsigned char* Ab = Al + buf * 32768;
    const unsigned char* Bb = Bl + buf * 32768;
    const int ktn = (T + 1) * 64;
    const bool pf = (T + 1 < 32);
#pragma unroll
    for (int ks = 0; ks < 2; ++ks) {
      bfrag af[8], bf0[2], bf1[2];
      // ================= phase 2ks+0 =================
#pragma unroll
      for (int fm = 0; fm < 8; ++fm)
        af[fm] = *(const bfrag*)(Ab + ks * 16384 + aro[fm]);
#pragma unroll
      for (int j = 0; j < 2; ++j)
        bf0[j] = *(const bfrag*)(Bb + ks * 16384 + bro[j]);
      if (pf) STAGE_A(buf ^ 1, ktn, ks);
      __builtin_amdgcn_sched_barrier(0);
      __builtin_amdgcn_s_barrier();
      asm volatile("s_waitcnt lgkmcnt(0)" ::: "memory");
      __builtin_amdgcn_sched_barrier(0);
      __builtin_amdgcn_s_setprio(1);
#pragma unroll
      for (int fm = 0; fm < 8; ++fm)
#pragma unroll
        for (int j = 0; j < 2; ++j)
          acc[fm][j] = __builtin_amdgcn_mfma_f32_16x16x32_bf16(af[fm], bf0[j],
                                                               acc[fm][j], 0, 0, 0);
      __builtin_amdgcn_s_setprio(0);
      __builtin_amdgcn_sched_barrier(0);
      __builtin_amdgcn_s_barrier();
      // ================= phase 2ks+1 =================
#pragma unroll
      for (int j = 0; j < 2; ++j)
        bf1[j] = *(const bfrag*)(Bb + ks * 16384 + bro[2 + j]);
      if (pf) STAGE_B(buf ^ 1, ktn, ks);
      __builtin_amdgcn_sched_barrier(0);
      __builtin_amdgcn_s_barrier();
      asm volatile("s_waitcnt lgkmcnt(0)" ::: "memory");
      __builtin_amdgcn_sched_barrier(0);
      __builtin_amdgcn_s_setprio(1);
#pragma unroll
      for (int fm = 0; fm < 8; ++fm)
#pragma unroll
        for (int j = 0; j < 2; ++j)
          acc[fm][2 + j] = __builtin_amdgcn_mfma_f32_16x16x32_bf16(af[fm], bf1[j],
                                                                   acc[fm][2 + j], 0, 0, 0);
      __builtin_amdgcn_s_setprio(0);
      __builtin_amdgcn_sched_barrier(0);
      if (T < 31) asm volatile("s_waitcnt vmcnt(4)" ::: "memory");
      else if (ks == 0) asm volatile("s_waitcnt vmcnt(0)" ::: "memory");
      __builtin_amdgcn_sched_barrier(0);
      __builtin_amdgcn_s_barrier();
    }
  }
#undef STAGE_A
#undef STAGE_B

  // ---- epilogue: direct global stores from registers (no LDS use)
  const float sc = (MODE == 3 && seg == 0) ? scale : 1.0f;
#pragma unroll
  for (int fm = 0; fm < 8; ++fm)
#pragma unroll
    for (int fn = 0; fn < 4; ++fn)
#pragma unroll
      for (int r = 0; r < 4; ++r) {
        int row = m0 + wm * 128 + fm * 16 + g * 4 + r;   // m = b*2048+s
        int col = n0 + wn * 64 + fn * 16 + cc;           // n = h*128+hd
        float v = acc[fm][fn][r];
        if (MODE == 3) {
          int b = row >> 11, s = row & 2047, h = col >> 7, hd = col & 127;
          unsigned short* D = (unsigned short*)Cout + (size_t)seg * 16777216;
          if (seg < 2)
            D[(((size_t)b * 16 + h) * 2048 + s) * 128 + hd] = f2bf(v * sc);
          else
            D[(((size_t)b * 16 + h) * 128 + hd) * 2048 + s] = f2bf(v);
        } else {
          ((float*)Cout)[(size_t)row * 2048 + col] = v;
        }
      }
}

// ---------------------------------------------------------------------------
// Flash attention, causal, swapped-operand, 32x32x16 MFMA.  (r7 structure +
// cvt_pk packing, T12.)
// Q,K: [B,H,S,HD] bf16 (Q prescaled by SMSCALE*L2E). Vt: [B,H,HD,S] bf16.
// O: [B,S,D] bf16. 8 waves x 32 q-rows, KVBLK=64, dbuf LDS, XOR swizzle.
// Dispatch: heavy-first qb = 7-(bx>>6)  (static; queue regressed in r9).
// ---------------------------------------------------------------------------
__global__ __launch_bounds__(512) void k_attn(const unsigned short* __restrict__ Q,
                                              const unsigned short* __restrict__ K,
                                              const unsigned short* __restrict__ Vt,
                                              unsigned short* __restrict__ O) {
  __shared__ __align__(16) unsigned char lds[65536];   // 2 x (16K K + 16K V)
  const int tid = threadIdx.x;
  const int ln = tid & 63, w = tid >> 6;
  const int l31 = ln & 31, hi = ln >> 5;
  const int rk = l31 & 15;
  const int bx = blockIdx.x;
  const int qb = 7 - (bx >> 6);          // heavy-first dispatch order
  const int bh = bx & 63;
  const int q0 = qb * 256;
  const size_t base = (size_t)bh * 2048 * 128;
  const unsigned short* Qb = Q + base;
  const unsigned short* Kb = K + base;
  const unsigned short* Vb = Vt + base;

  const int qw0 = q0 + w * 32;
  const int qg = qw0 + l31;

  // Q fragments (B-operand: col q = lane&31, d = dc*16 + hi*8 + j)
  bfrag qf[8];
#pragma unroll
  for (int dc = 0; dc < 8; ++dc)
    qf[dc] = *(const bfrag*)(Qb + (size_t)qg * 128 + dc * 16 + hi * 8);

  f32x16 o[4] = {};            // O^T acc: [d = db*32 + pat(r,hi)][q = lane&31]
  float m_r = NEGBIG, l_r = 0.f;

  const int nt = q0 / 64 + 4;

  // stage K tile [64][16ch] and V^T tile [64row'][16ch], XOR-16 swizzled
  auto stage = [&](int buf, int k0) {
    unsigned char* Kt = lds + buf * 32768;
    unsigned char* Vl = Kt + 16384;
#pragma unroll
    for (int i = 0; i < 2; ++i) {
      int cid = i * 512 + tid;
      int row = cid >> 4, p = cid & 15, sc = p ^ (row & 15);
      gload16(Kb + (size_t)(k0 + row) * 128 + sc * 8, Kt + cid * 16);
    }
#pragma unroll
    for (int i = 0; i < 2; ++i) {
      int cid = i * 512 + tid;
      int row = cid >> 4, p = cid & 15, sc = p ^ (row & 15);
      int d = (sc >> 3) * 64 + row;
      gload16(Vb + (size_t)d * 2048 + k0 + (sc & 7) * 8, Vl + cid * 16);
    }
  };

  stage(0, 0);
  DRAIN_VM;
  __syncthreads();
  int buf = 0;

  for (int t = 0; t < nt; ++t) {
    const int k0 = t * 64;
    if (t + 1 < nt) stage(buf ^ 1, k0 + 64);   // prefetch under compute

    if (k0 <= qw0 + 31) {                      // wave-uniform causal skip
      const unsigned char* Kt = lds + buf * 32768;
      const unsigned char* Vl = Kt + 16384;

      // ---- S^T = K * Q^T  (k rows, q cols)
      f32x16 s0 = {}, s1 = {};
#pragma unroll
      for (int dc = 0; dc < 8; ++dc) {
        int c = dc * 2 + hi;
        bfrag ka = *(const bfrag*)(Kt + (size_t)l31 * 256 + ((c ^ rk) << 4));
        bfrag kb2 = *(const bfrag*)(Kt + (size_t)(32 + l31) * 256 + ((c ^ rk) << 4));
        s0 = __builtin_amdgcn_mfma_f32_32x32x16_bf16(ka, qf[dc], s0, 0, 0, 0);
        s1 = __builtin_amdgcn_mfma_f32_32x32x16_bf16(kb2, qf[dc], s1, 0, 0, 0);
      }

      // ---- causal mask (diagonal tiles only)
      if (k0 + 63 > qw0) {
#pragma unroll
        for (int r = 0; r < 16; ++r) {
          int ko = (r & 3) + 8 * (r >> 2) + 4 * hi;
          if (k0 + ko > qg) s0[r] = NEGBIG;
          if (k0 + 32 + ko > qg) s1[r] = NEGBIG;
        }
      }

      // ---- row max
      float pmax = s0[0];
#pragma unroll
      for (int r = 1; r < 16; ++r) pmax = fmaxf(pmax, s0[r]);
#pragma unroll
      for (int r = 0; r < 16; ++r) pmax = fmaxf(pmax, s1[r]);
      pmax = fmaxf(pmax, __shfl_xor(pmax, 32));

      // ---- defer-max rescale (T13), log2 domain
      if (!__all(pmax - m_r <= 12.f)) {
        float mn = fmaxf(m_r, pmax);
        float al = EXP2(m_r - mn);
        l_r *= al;
#pragma unroll
        for (int db = 0; db < 4; ++db)
#pragma unroll
          for (int r = 0; r < 16; ++r) o[db][r] *= al;
        m_r = mn;
      }

      // ---- exp2 + pack to bf16 quads (v_cvt_pk_bf16_f32, T12)
      unsigned qd0[8], qd1[8];
      float rs = 0.f;
#pragma unroll
      for (int s = 0; s < 4; ++s) {
        float p0 = EXP2(s0[4 * s + 0] - m_r), p1 = EXP2(s0[4 * s + 1] - m_r);
        float p2 = EXP2(s0[4 * s + 2] - m_r), p3 = EXP2(s0[4 * s + 3] - m_r);
        rs += (p0 + p1) + (p2 + p3);
        qd0[2 * s] = cvtpk(p0, p1);
        qd0[2 * s + 1] = cvtpk(p2, p3);
      }
#pragma unroll
      for (int s = 0; s < 4; ++s) {
        float p0 = EXP2(s1[4 * s + 0] - m_r), p1 = EXP2(s1[4 * s + 1] - m_r);
        float p2 = EXP2(s1[4 * s + 2] - m_r), p3 = EXP2(s1[4 * s + 3] - m_r);
        rs += (p0 + p1) + (p2 + p3);
        qd1[2 * s] = cvtpk(p0, p1);
        qd1[2 * s + 1] = cvtpk(p2, p3);
      }
      rs += __shfl_xor(rs, 32);
      l_r += rs;

      // ---- O^T += V^T * P^T
#define PVSTEP(QD, B0, KC)                                                    \
  do {                                                                        \
    unsigned e0 = QD[B0], e1 = QD[B0 + 1], x0 = QD[B0 + 2], x1 = QD[B0 + 3];  \
    unsigned kp0 = hi ? x0 : e0, kp1 = hi ? x1 : e1;                          \
    unsigned sd0 = hi ? e0 : x0, sd1 = hi ? e1 : x1;                          \
    unsigned rc0 = (unsigned)__shfl_xor((int)sd0, 32);                        \
    unsigned rc1 = (unsigned)__shfl_xor((int)sd1, 32);                        \
    unsigned pw[4];                                                           \
    pw[0] = hi ? rc0 : kp0; pw[1] = hi ? rc1 : kp1;                           \
    pw[2] = hi ? kp0 : rc0; pw[3] = hi ? kp1 : rc1;                           \
    bfrag pf = *(bfrag*)pw;                                                   \
    _Pragma("unroll")                                                         \
    for (int db = 0; db < 4; ++db) {                                          \
      int c = (db >> 1) * 8 + KC * 2 + hi;                                    \
      bfrag vf = *(const bfrag*)(Vl + (size_t)((db & 1) * 32 + l31) * 256 +   \
                                 ((c ^ rk) << 4));                            \
      o[db] = __builtin_amdgcn_mfma_f32_32x32x16_bf16(vf, pf, o[db], 0, 0, 0);\
    }                                                                         \
  } while (0)

      PVSTEP(qd0, 0, 0);
      PVSTEP(qd0, 4, 1);
      PVSTEP(qd1, 0, 2);
      PVSTEP(qd1, 4, 3);
#undef PVSTEP
    }
    DRAIN_VM;
    __syncthreads();
    buf ^= 1;
  }

  // ---- epilogue: normalize, transpose O^T -> O via LDS (2 phases, 4 waves)
  float invl = 1.0f / l_r;
  const int b_ = bh >> 4, h_ = bh & 15;
#pragma unroll
  for (int ph = 0; ph < 2; ++ph) {
    if ((w >> 2) == ph) {
      unsigned char* ep = lds + (w & 3) * 8704;   // [32 q][136 d] bf16
#pragma unroll
      for (int db = 0; db < 4; ++db)
#pragma unroll
        for (int s = 0; s < 4; ++s) {
          int d0 = db * 32 + 8 * s + 4 * hi;
          float v0 = o[db][4 * s] * invl, v1 = o[db][4 * s + 1] * invl;
          float v2 = o[db][4 * s + 2] * invl, v3 = o[db][4 * s + 3] * invl;
          uint2 pw;
          pw.x = cvtpk(v0, v1);
          pw.y = cvtpk(v2, v3);
          *(uint2*)(ep + l31 * 272 + d0 * 2) = pw;
        }
    }
    __syncthreads();
    if ((w >> 2) == ph) {
      const unsigned char* ep = lds + (w & 3) * 8704;
#pragma unroll
      for (int i = 0; i < 8; ++i) {
        int cid = i * 64 + ln;
        int q = cid >> 4, ch = cid & 15;
        uint4 val = *(const uint4*)(ep + q * 272 + ch * 16);
        *(uint4*)(O + ((size_t)(b_ * 2048 + q0 + w * 32 + q)) * 2048 +
                  h_ * 128 + ch * 8) = val;
      }
    }
    __syncthreads();
  }
}

// ---------------------------------------------------------------------------
extern "C" void kernel_launch(void* const* d_in, const int* in_sizes, int n_in,
                              void* d_out, int out_size, void* d_ws, size_t ws_size,
                              hipStream_t stream) {
  (void)in_sizes; (void)n_in; (void)out_size; (void)ws_size;
  const float* x  = (const float*)d_in[0];
  /* d_in[1] = mask: causal tril, handled analytically */

  char* ws = (char*)d_ws;
  unsigned short* xbf  = (unsigned short*)ws;                        // 32 MiB
  unsigned short* Wall = (unsigned short*)(ws + (size_t)33554432);   // 32 MiB
  unsigned short* Qb   = (unsigned short*)(ws + (size_t)67108864);   // 3 x 32 MiB
  unsigned short* AO   = xbf;   // reuse x_bf16 buffer for attention output

  F4 f;
  f.W[0] = (const float*)d_in[2];  f.A[0] = (const float*)d_in[3];  f.Bm[0] = (const float*)d_in[4];
  f.W[1] = (const float*)d_in[5];  f.A[1] = (const float*)d_in[6];  f.Bm[1] = (const float*)d_in[7];
  f.W[2] = (const float*)d_in[8];  f.A[2] = (const float*)d_in[9];  f.Bm[2] = (const float*)d_in[10];
  f.W[3] = (const float*)d_in[11]; f.A[3] = (const float*)d_in[12]; f.Bm[3] = (const float*)d_in[13];

  k_prep<<<16384, 256, 0, stream>>>(f, x, xbf, Wall);

  // fused QKV: seg0 Q (prescaled) -> Qb, seg1 K -> Qb+16M, seg2 V^T -> Qb+32M
  k_gemm2<3><<<768, 512, 0, stream>>>(xbf, Wall, Qb, SMSCALE * L2E);

  k_attn<<<512, 512, 0, stream>>>(Qb, Qb + 16777216, Qb + 33554432, AO);

  k_gemm2<1><<<256, 512, 0, stream>>>(AO, Wall + 12582912, d_out, 1.0f);       // O
}

// Round 12
// 410.920 us; speedup vs baseline: 1.2102x; 1.0234x over previous
//
#include <hip/hip_runtime.h>
#include <hip/hip_bf16.h>
#include <stdint.h>

// ---------------------------------------------------------------------------
// LoRA attention, fully bf16-MFMA path.
//   y = x@(W + B@A)^T for q,k,v ; flash-attn causal (swapped-operand) ;
//   o-proj to fp32.
// Shapes: B=4 S=2048 D=2048 H=16 HD=128 R=16. M = B*S = 8192.
// ---------------------------------------------------------------------------

#define L2E 1.4426950408889634f
#define SMSCALE 0.08838834764831845f
#define NEGBIG -3.0e38f

typedef __attribute__((ext_vector_type(4))) float f32x4;
typedef __attribute__((ext_vector_type(16))) float f32x16;
typedef __attribute__((ext_vector_type(8))) __bf16 bfrag;   // 8 bf16 = 4 VGPR

#if __has_builtin(__builtin_amdgcn_exp2f)
#define EXP2 __builtin_amdgcn_exp2f
#else
#define EXP2 exp2f
#endif

// Explicit LDS-DMA drain: a late-landing global_load_lds must never cross a
// barrier into a region that gets read/reused (r2 replay-race lesson).
#define DRAIN_VM                                      \
  do {                                                \
    asm volatile("s_waitcnt vmcnt(0)" ::: "memory");  \
    __builtin_amdgcn_sched_barrier(0);                \
  } while (0)

static __device__ __forceinline__ unsigned short f2bf(float f) {
  union { float f; unsigned u; } v; v.f = f;
  unsigned r = v.u + 0x7FFFu + ((v.u >> 16) & 1u);   // RNE
  return (unsigned short)(r >> 16);
}

// packed f32x2 -> bf16x2 (RNE), 1 instr vs ~7 bit-ops (T12)
static __device__ __forceinline__ unsigned cvtpk(float lo, float hi) {
  unsigned r;
  asm("v_cvt_pk_bf16_f32 %0, %1, %2" : "=v"(r) : "v"(lo), "v"(hi));
  return r;
}

static __device__ __forceinline__ void gload16(const void* g, void* l) {
  __builtin_amdgcn_global_load_lds(
      (const __attribute__((address_space(1))) void*)g,
      (__attribute__((address_space(3))) void*)l, 16, 0, 0);
}

// ---------------------------------------------------------------------------
// Fused prep: blocks 0..8191 convert x -> bf16; blocks 8192..16383 fold
// Wall[y][n][k] = W_y[n][k] + sum_r B_y[n][r]*A_y[r][k] -> bf16 (y: q,k,v,o).
// ---------------------------------------------------------------------------
struct F4 {
  const float* W[4];
  const float* A[4];
  const float* Bm[4];
};

__global__ __launch_bounds__(256) void k_prep(F4 f, const float* __restrict__ x,
                                              unsigned short* __restrict__ xbf,
                                              unsigned short* __restrict__ Wall) {
  const int bid = blockIdx.x;
  if (bid < 8192) {
    const size_t i = ((size_t)bid * 256 + threadIdx.x) * 8;
    unsigned short o[8];
#pragma unroll
    for (int j = 0; j < 8; ++j) o[j] = f2bf(x[i + j]);
    *(uint4*)(xbf + i) = *(const uint4*)o;
    return;
  }
  const int y = (bid - 8192) >> 11;
  const int n = (bid - 8192) & 2047;
  const int k0 = threadIdx.x * 8;
  const float* W = f.W[y];
  const float* Aa = f.A[y];
  const float* Bm = f.Bm[y];
  const float* wr = W + (size_t)n * 2048 + k0;
  float acc[8];
#pragma unroll
  for (int j = 0; j < 8; ++j) acc[j] = wr[j];
#pragma unroll 4
  for (int r = 0; r < 16; ++r) {
    float b = Bm[n * 16 + r];
    const float* ar = Aa + (size_t)r * 2048 + k0;
#pragma unroll
    for (int j = 0; j < 8; ++j) acc[j] = fmaf(b, ar[j], acc[j]);
  }
  unsigned short o[8];
#pragma unroll
  for (int j = 0; j < 8; ++j) o[j] = f2bf(acc[j]);
  *(uint4*)(Wall + (((size_t)y * 2048 + n) * 2048) + k0) = *(const uint4*)o;
}

// ---------------------------------------------------------------------------
// GEMM2 (r7-exact, proven 410-us config): 256x256 tile, BK=64, 8 waves,
// 16x16x32 MFMA, 4-phase counted-vmcnt schedule, 128 KiB LDS.
//   C[m][n] = sum_k A[m][k] * Bw[n][k]
// LDS per operand: [2 buf][2 K-half][256 rows][32 k] bf16; chunk c of a row at
// LDS pos c ^ ((row>>1)&3) (bank-balanced, conflict-free b128 reads;
// SQ_LDS_BANK_CONFLICT = 0 measured r11).
// Ledger: vmcnt(4) retires the k-half consumed 2 phases later; stage ->
// overwrite margin >= 2 barriers; loads never drain mid-loop.
// MODE 0: bf16 -> [B,H,S,HD] scaled. MODE 1: fp32 flat. MODE 2: bf16 [B,H,HD,S].
// ---------------------------------------------------------------------------
template <int MODE>
__global__ __launch_bounds__(512, 2) void k_gemm2(const unsigned short* __restrict__ A,
                                                  const unsigned short* __restrict__ Bw,
                                                  void* __restrict__ Cout, float scale) {
  __shared__ __align__(16) unsigned char lds[131072];
  unsigned char* Al = lds;            // A: 2 x 32 KB
  unsigned char* Bl = lds + 65536;    // B: 2 x 32 KB
  const int tid = threadIdx.x, ln = tid & 63;
  const int w = tid >> 6, g = ln >> 4, cc = ln & 15;
  const int wm = w >> 2, wn = w & 3;
  const int bid = blockIdx.x;
  const int wg = (bid & 7) * 32 + (bid >> 3);   // bijective XCD swizzle (256 wgs)
  const int m0 = (wg >> 3) * 256, n0 = (wg & 7) * 256;

  int soff[2], sdst[2];
#pragma unroll
  for (int i = 0; i < 2; ++i) {
    int cid = i * 512 + tid, r = cid >> 2, p = cid & 3;
    int sc = p ^ ((r >> 1) & 3);
    soff[i] = r * 2048 + sc * 8;      // + base_row*2048 + kt + h*32
    sdst[i] = cid * 16;               // + buf*32768 + h*16384
  }
  int aro[8], bro[4];
#pragma unroll
  for (int fm = 0; fm < 8; ++fm) {
    int r = wm * 128 + fm * 16 + cc;
    aro[fm] = r * 64 + ((g ^ ((r >> 1) & 3)) << 4);
  }
#pragma unroll
  for (int fn = 0; fn < 4; ++fn) {
    int r = wn * 64 + fn * 16 + cc;
    bro[fn] = r * 64 + ((g ^ ((r >> 1) & 3)) << 4);
  }

#define STAGE_A(b, kt, h)                                                   \
  do {                                                                      \
    _Pragma("unroll")                                                       \
    for (int i = 0; i < 2; ++i)                                             \
      gload16(A + (size_t)m0 * 2048 + soff[i] + (kt) + (h) * 32,            \
              Al + (b) * 32768 + (h) * 16384 + sdst[i]);                    \
  } while (0)
#define STAGE_B(b, kt, h)                                                   \
  do {                                                                      \
    _Pragma("unroll")                                                       \
    for (int i = 0; i < 2; ++i)                                             \
      gload16(Bw + (size_t)n0 * 2048 + soff[i] + (kt) + (h) * 32,           \
              Bl + (b) * 32768 + (h) * 16384 + sdst[i]);                    \
  } while (0)

  f32x4 acc[8][4] = {};

  STAGE_A(0, 0, 0); STAGE_B(0, 0, 0);
  STAGE_A(0, 0, 1); STAGE_B(0, 0, 1);
  asm volatile("s_waitcnt vmcnt(4)" ::: "memory");
  __builtin_amdgcn_s_barrier();
  __builtin_amdgcn_sched_barrier(0);

  for (int T = 0; T < 32; ++T) {
    const int buf = T & 1;
    const unsigned char* Ab = Al + buf * 32768;
    const unsigned char* Bb = Bl + buf * 32768;
    const int ktn = (T + 1) * 64;
    const bool pf = (T + 1 < 32);
#pragma unroll
    for (int ks = 0; ks < 2; ++ks) {
      bfrag af[8], bf0[2], bf1[2];
      // ================= phase 2ks+0 =================
#pragma unroll
      for (int fm = 0; fm < 8; ++fm)
        af[fm] = *(const bfrag*)(Ab + ks * 16384 + aro[fm]);
#pragma unroll
      for (int j = 0; j < 2; ++j)
        bf0[j] = *(const bfrag*)(Bb + ks * 16384 + bro[j]);
      if (pf) STAGE_A(buf ^ 1, ktn, ks);
      __builtin_amdgcn_sched_barrier(0);
      __builtin_amdgcn_s_barrier();
      asm volatile("s_waitcnt lgkmcnt(0)" ::: "memory");
      __builtin_amdgcn_sched_barrier(0);
      __builtin_amdgcn_s_setprio(1);
#pragma unroll
      for (int fm = 0; fm < 8; ++fm)
#pragma unroll
        for (int j = 0; j < 2; ++j)
          acc[fm][j] = __builtin_amdgcn_mfma_f32_16x16x32_bf16(af[fm], bf0[j],
                                                               acc[fm][j], 0, 0, 0);
      __builtin_amdgcn_s_setprio(0);
      __builtin_amdgcn_sched_barrier(0);
      __builtin_amdgcn_s_barrier();
      // ================= phase 2ks+1 =================
#pragma unroll
      for (int j = 0; j < 2; ++j)
        bf1[j] = *(const bfrag*)(Bb + ks * 16384 + bro[2 + j]);
      if (pf) STAGE_B(buf ^ 1, ktn, ks);
      __builtin_amdgcn_sched_barrier(0);
      __builtin_amdgcn_s_barrier();
      asm volatile("s_waitcnt lgkmcnt(0)" ::: "memory");
      __builtin_amdgcn_sched_barrier(0);
      __builtin_amdgcn_s_setprio(1);
#pragma unroll
      for (int fm = 0; fm < 8; ++fm)
#pragma unroll
        for (int j = 0; j < 2; ++j)
          acc[fm][2 + j] = __builtin_amdgcn_mfma_f32_16x16x32_bf16(af[fm], bf1[j],
                                                                   acc[fm][2 + j], 0, 0, 0);
      __builtin_amdgcn_s_setprio(0);
      __builtin_amdgcn_sched_barrier(0);
      if (T < 31) asm volatile("s_waitcnt vmcnt(4)" ::: "memory");
      else if (ks == 0) asm volatile("s_waitcnt vmcnt(0)" ::: "memory");
      __builtin_amdgcn_sched_barrier(0);
      __builtin_amdgcn_s_barrier();
    }
  }
#undef STAGE_A
#undef STAGE_B

  // ---- epilogue: direct global stores from registers (no LDS use)
#pragma unroll
  for (int fm = 0; fm < 8; ++fm)
#pragma unroll
    for (int fn = 0; fn < 4; ++fn)
#pragma unroll
      for (int r = 0; r < 4; ++r) {
        int row = m0 + wm * 128 + fm * 16 + g * 4 + r;   // m = b*2048+s
        int col = n0 + wn * 64 + fn * 16 + cc;           // n = h*128+hd
        float v = acc[fm][fn][r];
        if (MODE == 0) {
          int b = row >> 11, s = row & 2047, h = col >> 7, hd = col & 127;
          ((unsigned short*)Cout)[(((size_t)b * 16 + h) * 2048 + s) * 128 + hd] =
              f2bf(v * scale);
        } else if (MODE == 2) {
          int b = row >> 11, s = row & 2047, h = col >> 7, hd = col & 127;
          ((unsigned short*)Cout)[(((size_t)b * 16 + h) * 128 + hd) * 2048 + s] =
              f2bf(v);
        } else {
          ((float*)Cout)[(size_t)row * 2048 + col] = v;
        }
      }
}

// ---------------------------------------------------------------------------
// Flash attention, causal, swapped-operand, 32x32x16 MFMA.  (r7 structure +
// cvt_pk packing (T12) + setprio around MFMA clusters (T5, attn-proven m191).)
// Q,K: [B,H,S,HD] bf16 (Q prescaled by SMSCALE*L2E). Vt: [B,H,HD,S] bf16.
// O: [B,S,D] bf16. 8 waves x 32 q-rows, KVBLK=64, dbuf LDS, XOR swizzle.
// Dispatch: heavy-first qb = 7-(bx>>6)  (static; queue regressed in r9).
// ---------------------------------------------------------------------------
__global__ __launch_bounds__(512) void k_attn(const unsigned short* __restrict__ Q,
                                              const unsigned short* __restrict__ K,
                                              const unsigned short* __restrict__ Vt,
                                              unsigned short* __restrict__ O) {
  __shared__ __align__(16) unsigned char lds[65536];   // 2 x (16K K + 16K V)
  const int tid = threadIdx.x;
  const int ln = tid & 63, w = tid >> 6;
  const int l31 = ln & 31, hi = ln >> 5;
  const int rk = l31 & 15;
  const int bx = blockIdx.x;
  const int qb = 7 - (bx >> 6);          // heavy-first dispatch order
  const int bh = bx & 63;
  const int q0 = qb * 256;
  const size_t base = (size_t)bh * 2048 * 128;
  const unsigned short* Qb = Q + base;
  const unsigned short* Kb = K + base;
  const unsigned short* Vb = Vt + base;

  const int qw0 = q0 + w * 32;
  const int qg = qw0 + l31;

  // Q fragments (B-operand: col q = lane&31, d = dc*16 + hi*8 + j)
  bfrag qf[8];
#pragma unroll
  for (int dc = 0; dc < 8; ++dc)
    qf[dc] = *(const bfrag*)(Qb + (size_t)qg * 128 + dc * 16 + hi * 8);

  f32x16 o[4] = {};            // O^T acc: [d = db*32 + pat(r,hi)][q = lane&31]
  float m_r = NEGBIG, l_r = 0.f;

  const int nt = q0 / 64 + 4;

  // stage K tile [64][16ch] and V^T tile [64row'][16ch], XOR-16 swizzled
  auto stage = [&](int buf, int k0) {
    unsigned char* Kt = lds + buf * 32768;
    unsigned char* Vl = Kt + 16384;
#pragma unroll
    for (int i = 0; i < 2; ++i) {
      int cid = i * 512 + tid;
      int row = cid >> 4, p = cid & 15, sc = p ^ (row & 15);
      gload16(Kb + (size_t)(k0 + row) * 128 + sc * 8, Kt + cid * 16);
    }
#pragma unroll
    for (int i = 0; i < 2; ++i) {
      int cid = i * 512 + tid;
      int row = cid >> 4, p = cid & 15, sc = p ^ (row & 15);
      int d = (sc >> 3) * 64 + row;
      gload16(Vb + (size_t)d * 2048 + k0 + (sc & 7) * 8, Vl + cid * 16);
    }
  };

  stage(0, 0);
  DRAIN_VM;
  __syncthreads();
  int buf = 0;

  for (int t = 0; t < nt; ++t) {
    const int k0 = t * 64;
    if (t + 1 < nt) stage(buf ^ 1, k0 + 64);   // prefetch under compute

    if (k0 <= qw0 + 31) {                      // wave-uniform causal skip
      const unsigned char* Kt = lds + buf * 32768;
      const unsigned char* Vl = Kt + 16384;

      // ---- S^T = K * Q^T  (k rows, q cols)  [T5: boost MFMA cluster]
      f32x16 s0 = {}, s1 = {};
      __builtin_amdgcn_s_setprio(1);
#pragma unroll
      for (int dc = 0; dc < 8; ++dc) {
        int c = dc * 2 + hi;
        bfrag ka = *(const bfrag*)(Kt + (size_t)l31 * 256 + ((c ^ rk) << 4));
        bfrag kb2 = *(const bfrag*)(Kt + (size_t)(32 + l31) * 256 + ((c ^ rk) << 4));
        s0 = __builtin_amdgcn_mfma_f32_32x32x16_bf16(ka, qf[dc], s0, 0, 0, 0);
        s1 = __builtin_amdgcn_mfma_f32_32x32x16_bf16(kb2, qf[dc], s1, 0, 0, 0);
      }
      __builtin_amdgcn_s_setprio(0);

      // ---- causal mask (diagonal tiles only)
      if (k0 + 63 > qw0) {
#pragma unroll
        for (int r = 0; r < 16; ++r) {
          int ko = (r & 3) + 8 * (r >> 2) + 4 * hi;
          if (k0 + ko > qg) s0[r] = NEGBIG;
          if (k0 + 32 + ko > qg) s1[r] = NEGBIG;
        }
      }

      // ---- row max
      float pmax = s0[0];
#pragma unroll
      for (int r = 1; r < 16; ++r) pmax = fmaxf(pmax, s0[r]);
#pragma unroll
      for (int r = 0; r < 16; ++r) pmax = fmaxf(pmax, s1[r]);
      pmax = fmaxf(pmax, __shfl_xor(pmax, 32));

      // ---- defer-max rescale (T13), log2 domain
      if (!__all(pmax - m_r <= 12.f)) {
        float mn = fmaxf(m_r, pmax);
        float al = EXP2(m_r - mn);
        l_r *= al;
#pragma unroll
        for (int db = 0; db < 4; ++db)
#pragma unroll
          for (int r = 0; r < 16; ++r) o[db][r] *= al;
        m_r = mn;
      }

      // ---- exp2 + pack to bf16 quads (v_cvt_pk_bf16_f32, T12)
      unsigned qd0[8], qd1[8];
      float rs = 0.f;
#pragma unroll
      for (int s = 0; s < 4; ++s) {
        float p0 = EXP2(s0[4 * s + 0] - m_r), p1 = EXP2(s0[4 * s + 1] - m_r);
        float p2 = EXP2(s0[4 * s + 2] - m_r), p3 = EXP2(s0[4 * s + 3] - m_r);
        rs += (p0 + p1) + (p2 + p3);
        qd0[2 * s] = cvtpk(p0, p1);
        qd0[2 * s + 1] = cvtpk(p2, p3);
      }
#pragma unroll
      for (int s = 0; s < 4; ++s) {
        float p0 = EXP2(s1[4 * s + 0] - m_r), p1 = EXP2(s1[4 * s + 1] - m_r);
        float p2 = EXP2(s1[4 * s + 2] - m_r), p3 = EXP2(s1[4 * s + 3] - m_r);
        rs += (p0 + p1) + (p2 + p3);
        qd1[2 * s] = cvtpk(p0, p1);
        qd1[2 * s + 1] = cvtpk(p2, p3);
      }
      rs += __shfl_xor(rs, 32);
      l_r += rs;

      // ---- O^T += V^T * P^T   [T5: boost MFMA cluster]
#define PVSTEP(QD, B0, KC)                                                    \
  do {                                                                        \
    unsigned e0 = QD[B0], e1 = QD[B0 + 1], x0 = QD[B0 + 2], x1 = QD[B0 + 3];  \
    unsigned kp0 = hi ? x0 : e0, kp1 = hi ? x1 : e1;                          \
    unsigned sd0 = hi ? e0 : x0, sd1 = hi ? e1 : x1;                          \
    unsigned rc0 = (unsigned)__shfl_xor((int)sd0, 32);                        \
    unsigned rc1 = (unsigned)__shfl_xor((int)sd1, 32);                        \
    unsigned pw[4];                                                           \
    pw[0] = hi ? rc0 : kp0; pw[1] = hi ? rc1 : kp1;                           \
    pw[2] = hi ? kp0 : rc0; pw[3] = hi ? kp1 : rc1;                           \
    bfrag pf = *(bfrag*)pw;                                                   \
    __builtin_amdgcn_s_setprio(1);                                            \
    _Pragma("unroll")                                                         \
    for (int db = 0; db < 4; ++db) {                                          \
      int c = (db >> 1) * 8 + KC * 2 + hi;                                    \
      bfrag vf = *(const bfrag*)(Vl + (size_t)((db & 1) * 32 + l31) * 256 +   \
                                 ((c ^ rk) << 4));                            \
      o[db] = __builtin_amdgcn_mfma_f32_32x32x16_bf16(vf, pf, o[db], 0, 0, 0);\
    }                                                                         \
    __builtin_amdgcn_s_setprio(0);                                            \
  } while (0)

      PVSTEP(qd0, 0, 0);
      PVSTEP(qd0, 4, 1);
      PVSTEP(qd1, 0, 2);
      PVSTEP(qd1, 4, 3);
#undef PVSTEP
    }
    DRAIN_VM;
    __syncthreads();
    buf ^= 1;
  }

  // ---- epilogue: normalize, transpose O^T -> O via LDS (2 phases, 4 waves)
  float invl = 1.0f / l_r;
  const int b_ = bh >> 4, h_ = bh & 15;
#pragma unroll
  for (int ph = 0; ph < 2; ++ph) {
    if ((w >> 2) == ph) {
      unsigned char* ep = lds + (w & 3) * 8704;   // [32 q][136 d] bf16
#pragma unroll
      for (int db = 0; db < 4; ++db)
#pragma unroll
        for (int s = 0; s < 4; ++s) {
          int d0 = db * 32 + 8 * s + 4 * hi;
          float v0 = o[db][4 * s] * invl, v1 = o[db][4 * s + 1] * invl;
          float v2 = o[db][4 * s + 2] * invl, v3 = o[db][4 * s + 3] * invl;
          uint2 pw;
          pw.x = cvtpk(v0, v1);
          pw.y = cvtpk(v2, v3);
          *(uint2*)(ep + l31 * 272 + d0 * 2) = pw;
        }
    }
    __syncthreads();
    if ((w >> 2) == ph) {
      const unsigned char* ep = lds + (w & 3) * 8704;
#pragma unroll
      for (int i = 0; i < 8; ++i) {
        int cid = i * 64 + ln;
        int q = cid >> 4, ch = cid & 15;
        uint4 val = *(const uint4*)(ep + q * 272 + ch * 16);
        *(uint4*)(O + ((size_t)(b_ * 2048 + q0 + w * 32 + q)) * 2048 +
                  h_ * 128 + ch * 8) = val;
      }
    }
    __syncthreads();
  }
}

// ---------------------------------------------------------------------------
extern "C" void kernel_launch(void* const* d_in, const int* in_sizes, int n_in,
                              void* d_out, int out_size, void* d_ws, size_t ws_size,
                              hipStream_t stream) {
  (void)in_sizes; (void)n_in; (void)out_size; (void)ws_size;
  const float* x  = (const float*)d_in[0];
  /* d_in[1] = mask: causal tril, handled analytically */

  char* ws = (char*)d_ws;
  unsigned short* xbf  = (unsigned short*)ws;                        // 32 MiB
  unsigned short* Wall = (unsigned short*)(ws + (size_t)33554432);   // 32 MiB
  unsigned short* Qb   = (unsigned short*)(ws + (size_t)67108864);   // 3 x 32 MiB
  unsigned short* Kb   = Qb + 16777216;
  unsigned short* Vtb  = Kb + 16777216;
  unsigned short* AO   = xbf;   // reuse x_bf16 buffer for attention output

  F4 f;
  f.W[0] = (const float*)d_in[2];  f.A[0] = (const float*)d_in[3];  f.Bm[0] = (const float*)d_in[4];
  f.W[1] = (const float*)d_in[5];  f.A[1] = (const float*)d_in[6];  f.Bm[1] = (const float*)d_in[7];
  f.W[2] = (const float*)d_in[8];  f.A[2] = (const float*)d_in[9];  f.Bm[2] = (const float*)d_in[10];
  f.W[3] = (const float*)d_in[11]; f.A[3] = (const float*)d_in[12]; f.Bm[3] = (const float*)d_in[13];

  k_prep<<<16384, 256, 0, stream>>>(f, x, xbf, Wall);

  k_gemm2<0><<<256, 512, 0, stream>>>(xbf, Wall, Qb, SMSCALE * L2E);           // Q
  k_gemm2<0><<<256, 512, 0, stream>>>(xbf, Wall + 4194304, Kb, 1.0f);          // K
  k_gemm2<2><<<256, 512, 0, stream>>>(xbf, Wall + 8388608, Vtb, 1.0f);         // V^T

  k_attn<<<512, 512, 0, stream>>>(Qb, Kb, Vtb, AO);

  k_gemm2<1><<<256, 512, 0, stream>>>(AO, Wall + 12582912, d_out, 1.0f);       // O
}

// Round 13
// 404.436 us; speedup vs baseline: 1.2296x; 1.0160x over previous
//
#include <hip/hip_runtime.h>
#include <hip/hip_bf16.h>
#include <stdint.h>

// ---------------------------------------------------------------------------
// LoRA attention, fully bf16-MFMA path.
//   y = x@(W + B@A)^T for q,k,v ; flash-attn causal (swapped-operand) ;
//   o-proj to fp32.
// Shapes: B=4 S=2048 D=2048 H=16 HD=128 R=16. M = B*S = 8192.
// ---------------------------------------------------------------------------

#define L2E 1.4426950408889634f
#define SMSCALE 0.08838834764831845f
#define NEGBIG -3.0e38f

typedef __attribute__((ext_vector_type(4))) float f32x4;
typedef __attribute__((ext_vector_type(16))) float f32x16;
typedef __attribute__((ext_vector_type(8))) __bf16 bfrag;   // 8 bf16 = 4 VGPR

#if __has_builtin(__builtin_amdgcn_exp2f)
#define EXP2 __builtin_amdgcn_exp2f
#else
#define EXP2 exp2f
#endif

// Explicit LDS-DMA drain: a late-landing global_load_lds must never cross a
// barrier into a region that gets read/reused (r2 replay-race lesson).
#define DRAIN_VM                                      \
  do {                                                \
    asm volatile("s_waitcnt vmcnt(0)" ::: "memory");  \
    __builtin_amdgcn_sched_barrier(0);                \
  } while (0)

static __device__ __forceinline__ unsigned short f2bf(float f) {
  union { float f; unsigned u; } v; v.f = f;
  unsigned r = v.u + 0x7FFFu + ((v.u >> 16) & 1u);   // RNE
  return (unsigned short)(r >> 16);
}

// packed f32x2 -> bf16x2 (RNE), 1 instr vs ~7 bit-ops (T12)
static __device__ __forceinline__ unsigned cvtpk(float lo, float hi) {
  unsigned r;
  asm("v_cvt_pk_bf16_f32 %0, %1, %2" : "=v"(r) : "v"(lo), "v"(hi));
  return r;
}

static __device__ __forceinline__ void gload16(const void* g, void* l) {
  __builtin_amdgcn_global_load_lds(
      (const __attribute__((address_space(1))) void*)g,
      (__attribute__((address_space(3))) void*)l, 16, 0, 0);
}

// ---------------------------------------------------------------------------
// Fused fold (r7-proven shape): Wall[y][n][k] = W_y[n][k] + sum_r B_y[n][r] *
// A_y[r][k] -> bf16. y: 0=q 1=k 2=v 3=o. grid (2048, 4).
// ---------------------------------------------------------------------------
struct F4 {
  const float* W[4];
  const float* A[4];
  const float* Bm[4];
};

__global__ __launch_bounds__(256) void k_fold4(F4 f, unsigned short* __restrict__ out) {
  const int y = blockIdx.y;
  const int n = blockIdx.x;
  const int k0 = threadIdx.x * 8;
  const float* W = f.W[y];
  const float* Aa = f.A[y];
  const float* Bm = f.Bm[y];
  const float* wr = W + (size_t)n * 2048 + k0;
  float acc[8];
#pragma unroll
  for (int j = 0; j < 8; ++j) acc[j] = wr[j];
#pragma unroll 4
  for (int r = 0; r < 16; ++r) {
    float b = Bm[n * 16 + r];
    const float* ar = Aa + (size_t)r * 2048 + k0;
#pragma unroll
    for (int j = 0; j < 8; ++j) acc[j] = fmaf(b, ar[j], acc[j]);
  }
  unsigned short o[8];
#pragma unroll
  for (int j = 0; j < 8; ++j) o[j] = f2bf(acc[j]);
  *(uint4*)(out + (((size_t)y * 2048 + n) * 2048) + k0) = *(const uint4*)o;
}

// ---------------------------------------------------------------------------
__global__ __launch_bounds__(256) void k_cvt(const float* __restrict__ in,
                                             unsigned short* __restrict__ out) {
  const size_t i = ((size_t)blockIdx.x * 256 + threadIdx.x) * 8;
  unsigned short o[8];
#pragma unroll
  for (int j = 0; j < 8; ++j) o[j] = f2bf(in[i + j]);
  *(uint4*)(out + i) = *(const uint4*)o;
}

// ---------------------------------------------------------------------------
// GEMM2 (r7-exact, proven 410-us config): 256x256 tile, BK=64, 8 waves,
// 16x16x32 MFMA, 4-phase counted-vmcnt schedule, 128 KiB LDS.
//   C[m][n] = sum_k A[m][k] * Bw[n][k]
// LDS per operand: [2 buf][2 K-half][256 rows][32 k] bf16; chunk c of a row at
// LDS pos c ^ ((row>>1)&3) (bank-balanced, conflict-free b128 reads;
// SQ_LDS_BANK_CONFLICT = 0 measured r11).
// Ledger: vmcnt(4) retires the k-half consumed 2 phases later; stage ->
// overwrite margin >= 2 barriers; loads never drain mid-loop.
// MODE 0: bf16 -> [B,H,S,HD] scaled. MODE 1: fp32 flat. MODE 2: bf16 [B,H,HD,S].
// ---------------------------------------------------------------------------
template <int MODE>
__global__ __launch_bounds__(512, 2) void k_gemm2(const unsigned short* __restrict__ A,
                                                  const unsigned short* __restrict__ Bw,
                                                  void* __restrict__ Cout, float scale) {
  __shared__ __align__(16) unsigned char lds[131072];
  unsigned char* Al = lds;            // A: 2 x 32 KB
  unsigned char* Bl = lds + 65536;    // B: 2 x 32 KB
  const int tid = threadIdx.x, ln = tid & 63;
  const int w = tid >> 6, g = ln >> 4, cc = ln & 15;
  const int wm = w >> 2, wn = w & 3;
  const int bid = blockIdx.x;
  const int wg = (bid & 7) * 32 + (bid >> 3);   // bijective XCD swizzle (256 wgs)
  const int m0 = (wg >> 3) * 256, n0 = (wg & 7) * 256;

  int soff[2], sdst[2];
#pragma unroll
  for (int i = 0; i < 2; ++i) {
    int cid = i * 512 + tid, r = cid >> 2, p = cid & 3;
    int sc = p ^ ((r >> 1) & 3);
    soff[i] = r * 2048 + sc * 8;      // + base_row*2048 + kt + h*32
    sdst[i] = cid * 16;               // + buf*32768 + h*16384
  }
  int aro[8], bro[4];
#pragma unroll
  for (int fm = 0; fm < 8; ++fm) {
    int r = wm * 128 + fm * 16 + cc;
    aro[fm] = r * 64 + ((g ^ ((r >> 1) & 3)) << 4);
  }
#pragma unroll
  for (int fn = 0; fn < 4; ++fn) {
    int r = wn * 64 + fn * 16 + cc;
    bro[fn] = r * 64 + ((g ^ ((r >> 1) & 3)) << 4);
  }

#define STAGE_A(b, kt, h)                                                   \
  do {                                                                      \
    _Pragma("unroll")                                                       \
    for (int i = 0; i < 2; ++i)                                             \
      gload16(A + (size_t)m0 * 2048 + soff[i] + (kt) + (h) * 32,            \
              Al + (b) * 32768 + (h) * 16384 + sdst[i]);                    \
  } while (0)
#define STAGE_B(b, kt, h)                                                   \
  do {                                                                      \
    _Pragma("unroll")                                                       \
    for (int i = 0; i < 2; ++i)                                             \
      gload16(Bw + (size_t)n0 * 2048 + soff[i] + (kt) + (h) * 32,           \
              Bl + (b) * 32768 + (h) * 16384 + sdst[i]);                    \
  } while (0)

  f32x4 acc[8][4] = {};

  STAGE_A(0, 0, 0); STAGE_B(0, 0, 0);
  STAGE_A(0, 0, 1); STAGE_B(0, 0, 1);
  asm volatile("s_waitcnt vmcnt(4)" ::: "memory");
  __builtin_amdgcn_s_barrier();
  __builtin_amdgcn_sched_barrier(0);

  for (int T = 0; T < 32; ++T) {
    const int buf = T & 1;
    const unsigned char* Ab = Al + buf * 32768;
    const unsigned char* Bb = Bl + buf * 32768;
    const int ktn = (T + 1) * 64;
    const bool pf = (T + 1 < 32);
#pragma unroll
    for (int ks = 0; ks < 2; ++ks) {
      bfrag af[8], bf0[2], bf1[2];
      // ================= phase 2ks+0 =================
#pragma unroll
      for (int fm = 0; fm < 8; ++fm)
        af[fm] = *(const bfrag*)(Ab + ks * 16384 + aro[fm]);
#pragma unroll
      for (int j = 0; j < 2; ++j)
        bf0[j] = *(const bfrag*)(Bb + ks * 16384 + bro[j]);
      if (pf) STAGE_A(buf ^ 1, ktn, ks);
      __builtin_amdgcn_sched_barrier(0);
      __builtin_amdgcn_s_barrier();
      asm volatile("s_waitcnt lgkmcnt(0)" ::: "memory");
      __builtin_amdgcn_sched_barrier(0);
      __builtin_amdgcn_s_setprio(1);
#pragma unroll
      for (int fm = 0; fm < 8; ++fm)
#pragma unroll
        for (int j = 0; j < 2; ++j)
          acc[fm][j] = __builtin_amdgcn_mfma_f32_16x16x32_bf16(af[fm], bf0[j],
                                                               acc[fm][j], 0, 0, 0);
      __builtin_amdgcn_s_setprio(0);
      __builtin_amdgcn_sched_barrier(0);
      __builtin_amdgcn_s_barrier();
      // ================= phase 2ks+1 =================
#pragma unroll
      for (int j = 0; j < 2; ++j)
        bf1[j] = *(const bfrag*)(Bb + ks * 16384 + bro[2 + j]);
      if (pf) STAGE_B(buf ^ 1, ktn, ks);
      __builtin_amdgcn_sched_barrier(0);
      __builtin_amdgcn_s_barrier();
      asm volatile("s_waitcnt lgkmcnt(0)" ::: "memory");
      __builtin_amdgcn_sched_barrier(0);
      __builtin_amdgcn_s_setprio(1);
#pragma unroll
      for (int fm = 0; fm < 8; ++fm)
#pragma unroll
        for (int j = 0; j < 2; ++j)
          acc[fm][2 + j] = __builtin_amdgcn_mfma_f32_16x16x32_bf16(af[fm], bf1[j],
                                                                   acc[fm][2 + j], 0, 0, 0);
      __builtin_amdgcn_s_setprio(0);
      __builtin_amdgcn_sched_barrier(0);
      if (T < 31) asm volatile("s_waitcnt vmcnt(4)" ::: "memory");
      else if (ks == 0) asm volatile("s_waitcnt vmcnt(0)" ::: "memory");
      __builtin_amdgcn_sched_barrier(0);
      __builtin_amdgcn_s_barrier();
    }
  }
#undef STAGE_A
#undef STAGE_B

  // ---- epilogue: direct global stores from registers (no LDS use)
#pragma unroll
  for (int fm = 0; fm < 8; ++fm)
#pragma unroll
    for (int fn = 0; fn < 4; ++fn)
#pragma unroll
      for (int r = 0; r < 4; ++r) {
        int row = m0 + wm * 128 + fm * 16 + g * 4 + r;   // m = b*2048+s
        int col = n0 + wn * 64 + fn * 16 + cc;           // n = h*128+hd
        float v = acc[fm][fn][r];
        if (MODE == 0) {
          int b = row >> 11, s = row & 2047, h = col >> 7, hd = col & 127;
          ((unsigned short*)Cout)[(((size_t)b * 16 + h) * 2048 + s) * 128 + hd] =
              f2bf(v * scale);
        } else if (MODE == 2) {
          int b = row >> 11, s = row & 2047, h = col >> 7, hd = col & 127;
          ((unsigned short*)Cout)[(((size_t)b * 16 + h) * 128 + hd) * 2048 + s] =
              f2bf(v);
        } else {
          ((float*)Cout)[(size_t)row * 2048 + col] = v;
        }
      }
}

// ---------------------------------------------------------------------------
// Flash attention, causal, swapped-operand, 32x32x16 MFMA.  (r12-exact:
// r7 structure + cvt_pk packing (T12) + setprio around MFMA clusters (T5);
// measured 97.4 us, MfmaUtil 30.4, VALUBusy 33.)
// Q,K: [B,H,S,HD] bf16 (Q prescaled by SMSCALE*L2E). Vt: [B,H,HD,S] bf16.
// O: [B,S,D] bf16. 8 waves x 32 q-rows, KVBLK=64, dbuf LDS, XOR swizzle.
// Dispatch: heavy-first qb = 7-(bx>>6)  (static; queue regressed in r9).
// ---------------------------------------------------------------------------
__global__ __launch_bounds__(512) void k_attn(const unsigned short* __restrict__ Q,
                                              const unsigned short* __restrict__ K,
                                              const unsigned short* __restrict__ Vt,
                                              unsigned short* __restrict__ O) {
  __shared__ __align__(16) unsigned char lds[65536];   // 2 x (16K K + 16K V)
  const int tid = threadIdx.x;
  const int ln = tid & 63, w = tid >> 6;
  const int l31 = ln & 31, hi = ln >> 5;
  const int rk = l31 & 15;
  const int bx = blockIdx.x;
  const int qb = 7 - (bx >> 6);          // heavy-first dispatch order
  const int bh = bx & 63;
  const int q0 = qb * 256;
  const size_t base = (size_t)bh * 2048 * 128;
  const unsigned short* Qb = Q + base;
  const unsigned short* Kb = K + base;
  const unsigned short* Vb = Vt + base;

  const int qw0 = q0 + w * 32;
  const int qg = qw0 + l31;

  // Q fragments (B-operand: col q = lane&31, d = dc*16 + hi*8 + j)
  bfrag qf[8];
#pragma unroll
  for (int dc = 0; dc < 8; ++dc)
    qf[dc] = *(const bfrag*)(Qb + (size_t)qg * 128 + dc * 16 + hi * 8);

  f32x16 o[4] = {};            // O^T acc: [d = db*32 + pat(r,hi)][q = lane&31]
  float m_r = NEGBIG, l_r = 0.f;

  const int nt = q0 / 64 + 4;

  // stage K tile [64][16ch] and V^T tile [64row'][16ch], XOR-16 swizzled
  auto stage = [&](int buf, int k0) {
    unsigned char* Kt = lds + buf * 32768;
    unsigned char* Vl = Kt + 16384;
#pragma unroll
    for (int i = 0; i < 2; ++i) {
      int cid = i * 512 + tid;
      int row = cid >> 4, p = cid & 15, sc = p ^ (row & 15);
      gload16(Kb + (size_t)(k0 + row) * 128 + sc * 8, Kt + cid * 16);
    }
#pragma unroll
    for (int i = 0; i < 2; ++i) {
      int cid = i * 512 + tid;
      int row = cid >> 4, p = cid & 15, sc = p ^ (row & 15);
      int d = (sc >> 3) * 64 + row;
      gload16(Vb + (size_t)d * 2048 + k0 + (sc & 7) * 8, Vl + cid * 16);
    }
  };

  stage(0, 0);
  DRAIN_VM;
  __syncthreads();
  int buf = 0;

  for (int t = 0; t < nt; ++t) {
    const int k0 = t * 64;
    if (t + 1 < nt) stage(buf ^ 1, k0 + 64);   // prefetch under compute

    if (k0 <= qw0 + 31) {                      // wave-uniform causal skip
      const unsigned char* Kt = lds + buf * 32768;
      const unsigned char* Vl = Kt + 16384;

      // ---- S^T = K * Q^T  (k rows, q cols)  [T5: boost MFMA cluster]
      f32x16 s0 = {}, s1 = {};
      __builtin_amdgcn_s_setprio(1);
#pragma unroll
      for (int dc = 0; dc < 8; ++dc) {
        int c = dc * 2 + hi;
        bfrag ka = *(const bfrag*)(Kt + (size_t)l31 * 256 + ((c ^ rk) << 4));
        bfrag kb2 = *(const bfrag*)(Kt + (size_t)(32 + l31) * 256 + ((c ^ rk) << 4));
        s0 = __builtin_amdgcn_mfma_f32_32x32x16_bf16(ka, qf[dc], s0, 0, 0, 0);
        s1 = __builtin_amdgcn_mfma_f32_32x32x16_bf16(kb2, qf[dc], s1, 0, 0, 0);
      }
      __builtin_amdgcn_s_setprio(0);

      // ---- causal mask (diagonal tiles only)
      if (k0 + 63 > qw0) {
#pragma unroll
        for (int r = 0; r < 16; ++r) {
          int ko = (r & 3) + 8 * (r >> 2) + 4 * hi;
          if (k0 + ko > qg) s0[r] = NEGBIG;
          if (k0 + 32 + ko > qg) s1[r] = NEGBIG;
        }
      }

      // ---- row max
      float pmax = s0[0];
#pragma unroll
      for (int r = 1; r < 16; ++r) pmax = fmaxf(pmax, s0[r]);
#pragma unroll
      for (int r = 0; r < 16; ++r) pmax = fmaxf(pmax, s1[r]);
      pmax = fmaxf(pmax, __shfl_xor(pmax, 32));

      // ---- defer-max rescale (T13), log2 domain
      if (!__all(pmax - m_r <= 12.f)) {
        float mn = fmaxf(m_r, pmax);
        float al = EXP2(m_r - mn);
        l_r *= al;
#pragma unroll
        for (int db = 0; db < 4; ++db)
#pragma unroll
          for (int r = 0; r < 16; ++r) o[db][r] *= al;
        m_r = mn;
      }

      // ---- exp2 + pack to bf16 quads (v_cvt_pk_bf16_f32, T12)
      unsigned qd0[8], qd1[8];
      float rs = 0.f;
#pragma unroll
      for (int s = 0; s < 4; ++s) {
        float p0 = EXP2(s0[4 * s + 0] - m_r), p1 = EXP2(s0[4 * s + 1] - m_r);
        float p2 = EXP2(s0[4 * s + 2] - m_r), p3 = EXP2(s0[4 * s + 3] - m_r);
        rs += (p0 + p1) + (p2 + p3);
        qd0[2 * s] = cvtpk(p0, p1);
        qd0[2 * s + 1] = cvtpk(p2, p3);
      }
#pragma unroll
      for (int s = 0; s < 4; ++s) {
        float p0 = EXP2(s1[4 * s + 0] - m_r), p1 = EXP2(s1[4 * s + 1] - m_r);
        float p2 = EXP2(s1[4 * s + 2] - m_r), p3 = EXP2(s1[4 * s + 3] - m_r);
        rs += (p0 + p1) + (p2 + p3);
        qd1[2 * s] = cvtpk(p0, p1);
        qd1[2 * s + 1] = cvtpk(p2, p3);
      }
      rs += __shfl_xor(rs, 32);
      l_r += rs;

      // ---- O^T += V^T * P^T   [T5: boost MFMA cluster]
#define PVSTEP(QD, B0, KC)                                                    \
  do {                                                                        \
    unsigned e0 = QD[B0], e1 = QD[B0 + 1], x0 = QD[B0 + 2], x1 = QD[B0 + 3];  \
    unsigned kp0 = hi ? x0 : e0, kp1 = hi ? x1 : e1;                          \
    unsigned sd0 = hi ? e0 : x0, sd1 = hi ? e1 : x1;                          \
    unsigned rc0 = (unsigned)__shfl_xor((int)sd0, 32);                        \
    unsigned rc1 = (unsigned)__shfl_xor((int)sd1, 32);                        \
    unsigned pw[4];                                                           \
    pw[0] = hi ? rc0 : kp0; pw[1] = hi ? rc1 : kp1;                           \
    pw[2] = hi ? kp0 : rc0; pw[3] = hi ? kp1 : rc1;                           \
    bfrag pf = *(bfrag*)pw;                                                   \
    __builtin_amdgcn_s_setprio(1);                                            \
    _Pragma("unroll")                                                         \
    for (int db = 0; db < 4; ++db) {                                          \
      int c = (db >> 1) * 8 + KC * 2 + hi;                                    \
      bfrag vf = *(const bfrag*)(Vl + (size_t)((db & 1) * 32 + l31) * 256 +   \
                                 ((c ^ rk) << 4));                            \
      o[db] = __builtin_amdgcn_mfma_f32_32x32x16_bf16(vf, pf, o[db], 0, 0, 0);\
    }                                                                         \
    __builtin_amdgcn_s_setprio(0);                                            \
  } while (0)

      PVSTEP(qd0, 0, 0);
      PVSTEP(qd0, 4, 1);
      PVSTEP(qd1, 0, 2);
      PVSTEP(qd1, 4, 3);
#undef PVSTEP
    }
    DRAIN_VM;
    __syncthreads();
    buf ^= 1;
  }

  // ---- epilogue: normalize, transpose O^T -> O via LDS (2 phases, 4 waves)
  float invl = 1.0f / l_r;
  const int b_ = bh >> 4, h_ = bh & 15;
#pragma unroll
  for (int ph = 0; ph < 2; ++ph) {
    if ((w >> 2) == ph) {
      unsigned char* ep = lds + (w & 3) * 8704;   // [32 q][136 d] bf16
#pragma unroll
      for (int db = 0; db < 4; ++db)
#pragma unroll
        for (int s = 0; s < 4; ++s) {
          int d0 = db * 32 + 8 * s + 4 * hi;
          float v0 = o[db][4 * s] * invl, v1 = o[db][4 * s + 1] * invl;
          float v2 = o[db][4 * s + 2] * invl, v3 = o[db][4 * s + 3] * invl;
          uint2 pw;
          pw.x = cvtpk(v0, v1);
          pw.y = cvtpk(v2, v3);
          *(uint2*)(ep + l31 * 272 + d0 * 2) = pw;
        }
    }
    __syncthreads();
    if ((w >> 2) == ph) {
      const unsigned char* ep = lds + (w & 3) * 8704;
#pragma unroll
      for (int i = 0; i < 8; ++i) {
        int cid = i * 64 + ln;
        int q = cid >> 4, ch = cid & 15;
        uint4 val = *(const uint4*)(ep + q * 272 + ch * 16);
        *(uint4*)(O + ((size_t)(b_ * 2048 + q0 + w * 32 + q)) * 2048 +
                  h_ * 128 + ch * 8) = val;
      }
    }
    __syncthreads();
  }
}

// ---------------------------------------------------------------------------
extern "C" void kernel_launch(void* const* d_in, const int* in_sizes, int n_in,
                              void* d_out, int out_size, void* d_ws, size_t ws_size,
                              hipStream_t stream) {
  (void)in_sizes; (void)n_in; (void)out_size; (void)ws_size;
  const float* x  = (const float*)d_in[0];
  /* d_in[1] = mask: causal tril, handled analytically */

  char* ws = (char*)d_ws;
  unsigned short* xbf  = (unsigned short*)ws;                        // 32 MiB
  unsigned short* Wall = (unsigned short*)(ws + (size_t)33554432);   // 32 MiB
  unsigned short* Qb   = (unsigned short*)(ws + (size_t)67108864);   // 3 x 32 MiB
  unsigned short* Kb   = Qb + 16777216;
  unsigned short* Vtb  = Kb + 16777216;
  unsigned short* AO   = xbf;   // reuse x_bf16 buffer for attention output

  F4 f;
  f.W[0] = (const float*)d_in[2];  f.A[0] = (const float*)d_in[3];  f.Bm[0] = (const float*)d_in[4];
  f.W[1] = (const float*)d_in[5];  f.A[1] = (const float*)d_in[6];  f.Bm[1] = (const float*)d_in[7];
  f.W[2] = (const float*)d_in[8];  f.A[2] = (const float*)d_in[9];  f.Bm[2] = (const float*)d_in[10];
  f.W[3] = (const float*)d_in[11]; f.A[3] = (const float*)d_in[12]; f.Bm[3] = (const float*)d_in[13];

  k_fold4<<<dim3(2048, 4), 256, 0, stream>>>(f, Wall);
  k_cvt<<<8192, 256, 0, stream>>>(x, xbf);

  k_gemm2<0><<<256, 512, 0, stream>>>(xbf, Wall, Qb, SMSCALE * L2E);           // Q
  k_gemm2<0><<<256, 512, 0, stream>>>(xbf, Wall + 4194304, Kb, 1.0f);          // K
  k_gemm2<2><<<256, 512, 0, stream>>>(xbf, Wall + 8388608, Vtb, 1.0f);         // V^T

  k_attn<<<512, 512, 0, stream>>>(Qb, Kb, Vtb, AO);

  k_gemm2<1><<<256, 512, 0, stream>>>(AO, Wall + 12582912, d_out, 1.0f);       // O
}